// Round 10
// baseline (493.191 us; speedup 1.0000x reference)
//
#include <hip/hip_runtime.h>
#include <cmath>

// Problem constants: B=32768, N=17, D=2, K=3, H=64
#define NBATCH 32768
#define NJOINT 17
#define OUT0_ELEMS (NBATCH * NJOINT * 15)          // out[B,N,3,5]
#define KJS_OFF    OUT0_ELEMS                      // k_js[B,N]
#define MASK_OFF   (KJS_OFF + NBATCH * NJOINT)     // mask[B,N,3]

#define WN_STRIDE 774
#define WS_DOUBLES (NJOINT * WN_STRIDE)

__device__ __forceinline__ float sel3f(int i, float a, float b, float c) {
    return (i == 0) ? a : ((i == 1) ? b : c);
}

// --------------------------------------------------------------------------
// Prelude: fp64 copies of k/w weights (escape path only).
// --------------------------------------------------------------------------
__global__ void cvt_weights_f64(
    const float* __restrict__ kW1, const float* __restrict__ kb1,
    const float* __restrict__ kW2, const float* __restrict__ kb2,
    const float* __restrict__ wW1, const float* __restrict__ wb1,
    const float* __restrict__ wW2, const float* __restrict__ wb2,
    double* __restrict__ dws)
{
    const int n = blockIdx.x;
    double* o = dws + (size_t)n * WN_STRIDE;
    for (int i = threadIdx.x; i < WN_STRIDE; i += blockDim.x) {
        int j = i;
        const float* W1 = kW1; const float* b1 = kb1;
        const float* W2 = kW2; const float* b2 = kb2;
        if (j >= 387) { j -= 387; W1 = wW1; b1 = wb1; W2 = wW2; b2 = wb2; }
        float v;
        if (j < 128)      v = W1[n * 128 + j];
        else if (j < 192) v = b1[n * 64 + (j - 128)];
        else if (j < 384) v = W2[n * 192 + (j - 192)];
        else              v = b2[n * 3 + (j - 384)];
        o[i] = (double)v;
    }
}

// --------------------------------------------------------------------------
// fp32 MLP (2 -> 64 -> 3) for TWO points, one s_load weight stream.
// --------------------------------------------------------------------------
__device__ __forceinline__ void mlp32_2(
    const float* __restrict__ W1, const float* __restrict__ b1f,
    const float* __restrict__ W2f, const float* __restrict__ b2f, int n,
    float xA0, float xA1, float xB0, float xB1,
    float& lA0, float& lA1, float& lA2,
    float& lB0, float& lB1, float& lB2)
{
    const float* W1a = W1 + n * 128;
    const float* W1b = W1a + 64;
    const float* b1  = b1f + n * 64;
    const float* W2  = W2f + n * 192;
    lA0 = b2f[n * 3 + 0]; lB0 = lA0;
    lA1 = b2f[n * 3 + 1]; lB1 = lA1;
    lA2 = b2f[n * 3 + 2]; lB2 = lA2;
    #pragma unroll 4
    for (int h = 0; h < 64; ++h) {
        const float wa = W1a[h], wb = W1b[h], bb = b1[h];
        const float w0 = W2[h * 3 + 0], w1 = W2[h * 3 + 1], w2 = W2[h * 3 + 2];
        float hvA = fmaxf(fmaf(xA1, wb, fmaf(xA0, wa, bb)), 0.0f);
        float hvB = fmaxf(fmaf(xB1, wb, fmaf(xB0, wa, bb)), 0.0f);
        lA0 = fmaf(hvA, w0, lA0); lB0 = fmaf(hvB, w0, lB0);
        lA1 = fmaf(hvA, w1, lA1); lB1 = fmaf(hvB, w1, lB1);
        lA2 = fmaf(hvA, w2, lA2); lB2 = fmaf(hvB, w2, lB2);
    }
}

// --------------------------------------------------------------------------
// fp64 escape: EXACT sequence of the proven passing kernels.
// --------------------------------------------------------------------------
__device__ __forceinline__ void mlp64_ws_1(
    const double* __restrict__ gws, double x0, double x1,
    double& l0, double& l1, double& l2)
{
    const double* W1a = gws;
    const double* W1b = gws + 64;
    const double* b1  = gws + 128;
    const double* W2  = gws + 192;
    l0 = gws[384]; l1 = gws[385]; l2 = gws[386];
    #pragma unroll 4
    for (int h = 0; h < 64; ++h) {
        double hv = fmax(fma(x1, W1b[h], fma(x0, W1a[h], b1[h])), 0.0);
        l0 = fma(hv, W2[h * 3 + 0], l0);
        l1 = fma(hv, W2[h * 3 + 1], l1);
        l2 = fma(hv, W2[h * 3 + 2], l2);
    }
}

__device__ __forceinline__ void mlp64_cvt_1(
    const float* __restrict__ W1, const float* __restrict__ b1f,
    const float* __restrict__ W2f, const float* __restrict__ b2f, int n,
    double x0, double x1, double& l0, double& l1, double& l2)
{
    const float* W1a = W1 + n * 128;
    const float* W1b = W1a + 64;
    const float* b1  = b1f + n * 64;
    const float* W2  = W2f + n * 192;
    l0 = (double)b2f[n * 3 + 0];
    l1 = (double)b2f[n * 3 + 1];
    l2 = (double)b2f[n * 3 + 2];
    #pragma unroll 4
    for (int h = 0; h < 64; ++h) {
        double hv = fma(x1, (double)W1b[h], fma(x0, (double)W1a[h], (double)b1[h]));
        hv = fmax(hv, 0.0);
        l0 = fma(hv, (double)W2[h * 3 + 0], l0);
        l1 = fma(hv, (double)W2[h * 3 + 1], l1);
        l2 = fma(hv, (double)W2[h * 3 + 2], l2);
    }
}

// margin check (r9-proven): ~3% wave escape rate.
__device__ __forceinline__ bool tight3(float a, float b, float c) {
    const float m01 = fabsf(a - b), m02 = fabsf(a - c), m12 = fabsf(b - c);
    const float mn = fminf(m01, fminf(m02, m12));
    const float tau = 2e-5f * (1.0f + 0.05f * (fabsf(a) + fabsf(b) + fabsf(c)));
    return mn < tau;
}

// decisions + softmax from (double) logits — identical to passing kernels.
__device__ __forceinline__ void decide(
    double kl0, double kl1, double kl2,
    double wl0, double wl1, double wl2,
    int& kj, int& i0, int& i1, int& i2,
    float& p0, float& p1, float& p2)
{
    kj = 0;
    {
        double m = kl0;
        if (kl1 > m) { m = kl1; kj = 1; }
        if (kl2 > m) { kj = 2; }
    }
    i0 = 0;
    {
        double m = wl0;
        if (wl1 > m) { m = wl1; i0 = 1; }
        if (wl2 > m) { i0 = 2; }
    }
    const int ia = (i0 == 0) ? 1 : 0;
    const int ib = (i0 == 2) ? 1 : 2;
    const double wa = ia ? wl1 : wl0;
    const double wb = (ib == 1) ? wl1 : wl2;
    i1 = (wb > wa) ? ib : ia;
    i2 = (wb > wa) ? ia : ib;

    const double mw = fmax(fmax(wl0, wl1), wl2);
    const float e0 = __expf((float)(wl0 - mw));
    const float e1 = __expf((float)(wl1 - mw));
    const float e2 = __expf((float)(wl2 - mw));
    const float inv = 1.0f / (e0 + e1 + e2);
    p0 = e0 * inv; p1 = e1 * inv; p2 = e2 * inv;
}

__device__ __forceinline__ void epilogue(
    const float acc[12], int i0, int i1, int i2,
    float p0, float p1, float p2, float r[15])
{
    r[0]  = p0; r[5] = p1; r[10] = p2;
    r[1]  = sel3f(i0, acc[0], acc[4], acc[8]);
    r[2]  = sel3f(i0, acc[1], acc[5], acc[9]);
    r[3]  = __expf(sel3f(i0, acc[2], acc[6], acc[10]));
    r[4]  = __expf(sel3f(i0, acc[3], acc[7], acc[11]));
    r[6]  = sel3f(i1, acc[0], acc[4], acc[8]);
    r[7]  = sel3f(i1, acc[1], acc[5], acc[9]);
    r[8]  = __expf(sel3f(i1, acc[2], acc[6], acc[10]));
    r[9]  = __expf(sel3f(i1, acc[3], acc[7], acc[11]));
    r[11] = sel3f(i2, acc[0], acc[4], acc[8]);
    r[12] = sel3f(i2, acc[1], acc[5], acc[9]);
    r[13] = __expf(sel3f(i2, acc[2], acc[6], acc[10]));
    r[14] = __expf(sel3f(i2, acc[3], acc[7], acc[11]));
}

// --------------------------------------------------------------------------
// r9 compute2 (unchanged, best-known passing path).
// --------------------------------------------------------------------------
template<bool USE_WS>
__device__ __forceinline__ void compute2(
    int n, float xA0f, float xA1f, float xB0f, float xB1f,
    const float* __restrict__ kW1, const float* __restrict__ kb1,
    const float* __restrict__ kW2, const float* __restrict__ kb2,
    const float* __restrict__ wW1, const float* __restrict__ wb1,
    const float* __restrict__ wW2, const float* __restrict__ wb2,
    const float* __restrict__ bW1, const float* __restrict__ bb1,
    const float* __restrict__ bW2, const float* __restrict__ bb2,
    const double* __restrict__ dws,
    float rA[15], float rB[15], int& kjA, int& kjB)
{
    float kA0, kA1, kA2, kB0, kB1, kB2;
    float wA0, wA1, wA2, wB0, wB1, wB2;
    mlp32_2(kW1, kb1, kW2, kb2, n, xA0f, xA1f, xB0f, xB1f,
            kA0, kA1, kA2, kB0, kB1, kB2);
    mlp32_2(wW1, wb1, wW2, wb2, n, xA0f, xA1f, xB0f, xB1f,
            wA0, wA1, wA2, wB0, wB1, wB2);

    const bool fA = tight3(kA0, kA1, kA2) || tight3(wA0, wA1, wA2);
    const bool fB = tight3(kB0, kB1, kB2) || tight3(wB0, wB1, wB2);

    double klA0 = kA0, klA1 = kA1, klA2 = kA2;
    double klB0 = kB0, klB1 = kB1, klB2 = kB2;
    double wlA0 = wA0, wlA1 = wA1, wlA2 = wA2;
    double wlB0 = wB0, wlB1 = wB1, wlB2 = wB2;

    if (__any(fA || fB)) {
        if constexpr (USE_WS) {
            const double* Wn = dws + (size_t)n * WN_STRIDE;
            if (fA) {
                mlp64_ws_1(Wn,       (double)xA0f, (double)xA1f, klA0, klA1, klA2);
                mlp64_ws_1(Wn + 387, (double)xA0f, (double)xA1f, wlA0, wlA1, wlA2);
            }
            if (fB) {
                mlp64_ws_1(Wn,       (double)xB0f, (double)xB1f, klB0, klB1, klB2);
                mlp64_ws_1(Wn + 387, (double)xB0f, (double)xB1f, wlB0, wlB1, wlB2);
            }
        } else {
            if (fA) {
                mlp64_cvt_1(kW1, kb1, kW2, kb2, n, (double)xA0f, (double)xA1f, klA0, klA1, klA2);
                mlp64_cvt_1(wW1, wb1, wW2, wb2, n, (double)xA0f, (double)xA1f, wlA0, wlA1, wlA2);
            }
            if (fB) {
                mlp64_cvt_1(kW1, kb1, kW2, kb2, n, (double)xB0f, (double)xB1f, klB0, klB1, klB2);
                mlp64_cvt_1(wW1, wb1, wW2, wb2, n, (double)xB0f, (double)xB1f, wlB0, wlB1, wlB2);
            }
        }
    }

    int i0A, i1A, i2A, i0B, i1B, i2B;
    float p0A, p1A, p2A, p0B, p1B, p2B;
    decide(klA0, klA1, klA2, wlA0, wlA1, wlA2, kjA, i0A, i1A, i2A, p0A, p1A, p2A);
    decide(klB0, klB1, klB2, wlB0, wlB1, wlB2, kjB, i0B, i1B, i2B, p0B, p1B, p2B);

    float accA[12], accB[12];
    {
        const float* W1a = bW1 + n * 256;
        const float* W1b = W1a + 128;
        const float* b1  = bb1 + n * 128;
        const float* W2  = bW2 + n * 1536;
        const float* b2  = bb2 + n * 12;
        #pragma unroll
        for (int j = 0; j < 12; ++j) { accA[j] = b2[j]; accB[j] = b2[j]; }
        #pragma unroll 4
        for (int h = 0; h < 128; ++h) {
            const float wa = W1a[h], wb = W1b[h], bb = b1[h];
            float hvA = fmaxf(fmaf(xA1f, wb, fmaf(xA0f, wa, bb)), 0.0f);
            float hvB = fmaxf(fmaf(xB1f, wb, fmaf(xB0f, wa, bb)), 0.0f);
            #pragma unroll
            for (int j = 0; j < 12; ++j) {
                const float wv = W2[h * 12 + j];
                accA[j] = fmaf(hvA, wv, accA[j]);
                accB[j] = fmaf(hvB, wv, accB[j]);
            }
        }
    }

    epilogue(accA, i0A, i1A, i2A, p0A, p1A, p2A, rA);
    epilogue(accB, i0B, i1B, i2B, p0B, p1B, p2B, rB);
}

// --------------------------------------------------------------------------
// REAL kernel — byte-identical structure to r9 (best known, passes).
// --------------------------------------------------------------------------
template<bool USE_WS>
__global__ __launch_bounds__(128, 4) void mdn_fused(
    const float* __restrict__ pred_pts,
    const float* __restrict__ kW1, const float* __restrict__ kb1,
    const float* __restrict__ kW2, const float* __restrict__ kb2,
    const float* __restrict__ wW1, const float* __restrict__ wb1,
    const float* __restrict__ wW2, const float* __restrict__ wb2,
    const float* __restrict__ bW1, const float* __restrict__ bb1,
    const float* __restrict__ bW2, const float* __restrict__ bb2,
    float* __restrict__ out,
    const double* __restrict__ dws)
{
    const int l    = threadIdx.x;
    const int w    = l >> 6;
    const int lane = l & 63;
    const int bx   = blockIdx.x;
    const int by   = blockIdx.y;
    const int n0   = by * 2;

    if (by == 8 && w == 1) return;
    int n = n0 + w;
    n = __builtin_amdgcn_readfirstlane(n);

    const int bA = bx * 128 + lane;
    const int bB = bA + 64;
    const int pA = bA * NJOINT + n;
    const int pB = bB * NJOINT + n;

    const float2 xA = *reinterpret_cast<const float2*>(pred_pts + 2 * pA);
    const float2 xB = *reinterpret_cast<const float2*>(pred_pts + 2 * pB);

    float rA[15], rB[15];
    int kjA, kjB;
    compute2<USE_WS>(n, xA.x, xA.y, xB.x, xB.y,
                     kW1, kb1, kW2, kb2, wW1, wb1, wW2, wb2,
                     bW1, bb1, bW2, bb2, dws, rA, rB, kjA, kjB);

    if (by == 8) {
        float* oA = out + (size_t)pA * 15;
        float* oB = out + (size_t)pB * 15;
        #pragma unroll
        for (int i = 0; i < 15; ++i) { oA[i] = rA[i]; oB[i] = rB[i]; }
        out[KJS_OFF + pA] = (float)(kjA + 1);
        out[KJS_OFF + pB] = (float)(kjB + 1);
        float* mkA = out + MASK_OFF + (size_t)pA * 3;
        mkA[0] = 1.0f; mkA[1] = (kjA >= 1) ? 1.0f : 0.0f; mkA[2] = (kjA >= 2) ? 1.0f : 0.0f;
        float* mkB = out + MASK_OFF + (size_t)pB * 3;
        mkB[0] = 1.0f; mkB[1] = (kjB >= 1) ? 1.0f : 0.0f; mkB[2] = (kjB >= 2) ? 1.0f : 0.0f;
        return;
    }

    __shared__ float s_out[256 * 17];
    {
        float* soA = s_out + (w * 128 + lane) * 17;
        float* soB = soA + 64 * 17;
        #pragma unroll
        for (int j = 0; j < 15; ++j) { soA[j] = rA[j]; soB[j] = rB[j]; }
        soA[15] = (float)(kjA + 1);
        soB[15] = (float)(kjB + 1);
    }
    __syncthreads();

    if (l < 120) {
        const int c_off = l / 30;
        const int jj    = l - c_off * 30;
        const int nl    = jj / 15;
        const int j     = jj - nl * 15;
        const int lbase = (nl * 128 + c_off) * 17 + j;
        size_t g = (size_t)((bx * 128 + c_off) * NJOINT + n0) * 15 + jj;
        #pragma unroll
        for (int rr = 0; rr < 32; ++rr) {
            out[g] = s_out[lbase + 68 * rr];
            g += 1020;
        }
    }

    #pragma unroll
    for (int it = 0; it < 2; ++it) {
        const int q   = it * 128 + l;
        const int bl  = q >> 1;
        const int nlr = q & 1;
        const float kjf = s_out[(nlr * 128 + bl) * 17 + 15];
        const int pg = (bx * 128 + bl) * NJOINT + n0 + nlr;
        out[KJS_OFF + pg] = kjf;
        float* mk = out + MASK_OFF + (size_t)pg * 3;
        mk[0] = 1.0f;
        mk[1] = (kjf >= 1.5f) ? 1.0f : 0.0f;
        mk[2] = (kjf >= 2.5f) ? 1.0f : 0.0f;
    }
}

// ==========================================================================
// DIAGNOSTIC PROBE: exact r9 op sequence with SYNTHETIC in-register weights
// (no weight loads, no waitcnts). 3 data-chained compute passes + one full
// store pass: T_probe = 3*C_noload + S. Runs BEFORE the real kernel; real
// kernel overwrites every output byte -> correctness unaffected.
// Weight banks: periods 13/5/7 (lcm 455 > any loop) -> no CSE collapse.
// ==========================================================================
__device__ __forceinline__ float mkw(float x) {
    // runtime-opaque float in [1,2): no inf/nan/denormal timing artifacts
    return __int_as_float((__float_as_int(x) & 0x007FFFFF) | 0x3F800000);
}

template<int OFF>
__device__ __forceinline__ void synth_mlp32_2(
    const float* v13, const float* v5b, const float* v7b,
    float xA0, float xA1, float xB0, float xB1,
    float& lA0, float& lA1, float& lA2,
    float& lB0, float& lB1, float& lB2)
{
    lA0 = v13[OFF % 13];       lB0 = lA0;
    lA1 = v13[(OFF + 1) % 13]; lB1 = lA1;
    lA2 = v13[(OFF + 2) % 13]; lB2 = lA2;
    #pragma unroll
    for (int h = 0; h < 64; ++h) {
        const float wa = v13[(6 * h + OFF) % 13];
        const float wb = v5b[(3 * h + OFF) % 5];
        const float bb = v7b[(2 * h + OFF) % 7];
        const float w0 = v13[(6 * h + 3 + OFF) % 13];
        const float w1 = v5b[(3 * h + 1 + OFF) % 5];
        const float w2 = v7b[(2 * h + 4 + OFF) % 7];
        float hvA = fmaxf(fmaf(xA1, wb, fmaf(xA0, wa, bb)), 0.0f);
        float hvB = fmaxf(fmaf(xB1, wb, fmaf(xB0, wa, bb)), 0.0f);
        lA0 = fmaf(hvA, w0, lA0); lB0 = fmaf(hvB, w0, lB0);
        lA1 = fmaf(hvA, w1, lA1); lB1 = fmaf(hvB, w1, lB1);
        lA2 = fmaf(hvA, w2, lA2); lB2 = fmaf(hvB, w2, lB2);
    }
}

__global__ __launch_bounds__(128, 2) void mdn_probe_nl(
    const float* __restrict__ pred_pts, float* __restrict__ out)
{
    const int l    = threadIdx.x;
    const int w    = l >> 6;
    const int lane = l & 63;
    const int bx   = blockIdx.x;
    const int by   = blockIdx.y;
    const int n0   = by * 2;

    if (by == 8 && w == 1) return;
    int n = n0 + w;
    n = __builtin_amdgcn_readfirstlane(n);

    float v13[13], v5b[5], v7b[7];
    #pragma unroll
    for (int i = 0; i < 13; ++i) v13[i] = mkw(pred_pts[i]);
    #pragma unroll
    for (int i = 0; i < 5; ++i)  v5b[i] = mkw(pred_pts[13 + i]);
    #pragma unroll
    for (int i = 0; i < 7; ++i)  v7b[i] = mkw(pred_pts[18 + i]);

    const int bA = bx * 128 + lane;
    const int bB = bA + 64;
    const int pA = bA * NJOINT + n;
    const int pB = bB * NJOINT + n;
    const float2 xAv = *reinterpret_cast<const float2*>(pred_pts + 2 * pA);
    const float2 xBv = *reinterpret_cast<const float2*>(pred_pts + 2 * pB);
    float xA0 = xAv.x, xA1 = xAv.y, xB0 = xBv.x, xB1 = xBv.y;

    float rA[15], rB[15];
    int kjA = 0, kjB = 0;

    #pragma unroll 1
    for (int pass = 0; pass < 3; ++pass) {
        float kA0, kA1, kA2, kB0, kB1, kB2;
        float wA0, wA1, wA2, wB0, wB1, wB2;
        synth_mlp32_2<0>(v13, v5b, v7b, xA0, xA1, xB0, xB1,
                         kA0, kA1, kA2, kB0, kB1, kB2);
        synth_mlp32_2<1>(v13, v5b, v7b, xA0, xA1, xB0, xB1,
                         wA0, wA1, wA2, wB0, wB1, wB2);

        int i0A, i1A, i2A, i0B, i1B, i2B;
        float p0A, p1A, p2A, p0B, p1B, p2B;
        decide((double)kA0, (double)kA1, (double)kA2,
               (double)wA0, (double)wA1, (double)wA2,
               kjA, i0A, i1A, i2A, p0A, p1A, p2A);
        decide((double)kB0, (double)kB1, (double)kB2,
               (double)wB0, (double)wB1, (double)wB2,
               kjB, i0B, i1B, i2B, p0B, p1B, p2B);

        float accA[12], accB[12];
        #pragma unroll
        for (int j = 0; j < 12; ++j) { accA[j] = v13[j]; accB[j] = v13[j]; }
        #pragma unroll
        for (int h = 0; h < 128; ++h) {
            const float wa = v13[(3 * h) % 13];
            const float wb = v5b[(2 * h + 1) % 5];
            const float bb = v7b[(4 * h + 2) % 7];
            float hvA = fmaxf(fmaf(xA1, wb, fmaf(xA0, wa, bb)), 0.0f);
            float hvB = fmaxf(fmaf(xB1, wb, fmaf(xB0, wa, bb)), 0.0f);
            #pragma unroll
            for (int j = 0; j < 12; ++j) {
                const float wv = v13[(3 * h + 5 + j) % 13];
                accA[j] = fmaf(hvA, wv, accA[j]);
                accB[j] = fmaf(hvB, wv, accB[j]);
            }
        }

        epilogue(accA, i0A, i1A, i2A, p0A, p1A, p2A, rA);
        epilogue(accB, i0B, i1B, i2B, p0B, p1B, p2B, rB);

        if (pass < 2) {   // data-chain into next pass: defeats DCE, no stores
            xA0 = fmaf(rA[0] + rA[7] + rA[14], 1e-20f, xA0 * 1.000001f);
            xA1 = fmaf(rA[3] + rA[10] + (float)kjA, 1e-20f, xA1 * 1.000001f);
            xB0 = fmaf(rB[0] + rB[7] + rB[14], 1e-20f, xB0 * 1.000001f);
            xB1 = fmaf(rB[3] + rB[10] + (float)kjB, 1e-20f, xB1 * 1.000001f);
        }
    }

    // ---- store path, identical to real kernel (measures S once) ----
    if (by == 8) {
        float* oA = out + (size_t)pA * 15;
        float* oB = out + (size_t)pB * 15;
        #pragma unroll
        for (int i = 0; i < 15; ++i) { oA[i] = rA[i]; oB[i] = rB[i]; }
        out[KJS_OFF + pA] = (float)(kjA + 1);
        out[KJS_OFF + pB] = (float)(kjB + 1);
        float* mkA = out + MASK_OFF + (size_t)pA * 3;
        mkA[0] = 1.0f; mkA[1] = (kjA >= 1) ? 1.0f : 0.0f; mkA[2] = (kjA >= 2) ? 1.0f : 0.0f;
        float* mkB = out + MASK_OFF + (size_t)pB * 3;
        mkB[0] = 1.0f; mkB[1] = (kjB >= 1) ? 1.0f : 0.0f; mkB[2] = (kjB >= 2) ? 1.0f : 0.0f;
        return;
    }

    __shared__ float s_out[256 * 17];
    {
        float* soA = s_out + (w * 128 + lane) * 17;
        float* soB = soA + 64 * 17;
        #pragma unroll
        for (int j = 0; j < 15; ++j) { soA[j] = rA[j]; soB[j] = rB[j]; }
        soA[15] = (float)(kjA + 1);
        soB[15] = (float)(kjB + 1);
    }
    __syncthreads();

    if (l < 120) {
        const int c_off = l / 30;
        const int jj    = l - c_off * 30;
        const int nl    = jj / 15;
        const int j     = jj - nl * 15;
        const int lbase = (nl * 128 + c_off) * 17 + j;
        size_t g = (size_t)((bx * 128 + c_off) * NJOINT + n0) * 15 + jj;
        #pragma unroll
        for (int rr = 0; rr < 32; ++rr) {
            out[g] = s_out[lbase + 68 * rr];
            g += 1020;
        }
    }

    #pragma unroll
    for (int it = 0; it < 2; ++it) {
        const int q   = it * 128 + l;
        const int bl  = q >> 1;
        const int nlr = q & 1;
        const float kjf = s_out[(nlr * 128 + bl) * 17 + 15];
        const int pg = (bx * 128 + bl) * NJOINT + n0 + nlr;
        out[KJS_OFF + pg] = kjf;
        float* mk = out + MASK_OFF + (size_t)pg * 3;
        mk[0] = 1.0f;
        mk[1] = (kjf >= 1.5f) ? 1.0f : 0.0f;
        mk[2] = (kjf >= 2.5f) ? 1.0f : 0.0f;
    }
}

extern "C" void kernel_launch(void* const* d_in, const int* in_sizes, int n_in,
                              void* d_out, int out_size, void* d_ws, size_t ws_size,
                              hipStream_t stream) {
    (void)in_sizes; (void)n_in; (void)out_size;
    const bool use_ws = (d_ws != nullptr) && (ws_size >= (size_t)WS_DOUBLES * sizeof(double));
    dim3 grid(NBATCH / 128, 9);

    // diagnostic probe first (its writes are fully overwritten by the real kernel)
    mdn_probe_nl<<<grid, 128, 0, stream>>>((const float*)d_in[0], (float*)d_out);

    if (use_ws) {
        cvt_weights_f64<<<NJOINT, 256, 0, stream>>>(
            (const float*)d_in[1], (const float*)d_in[2],
            (const float*)d_in[3], (const float*)d_in[4],
            (const float*)d_in[5], (const float*)d_in[6],
            (const float*)d_in[7], (const float*)d_in[8],
            (double*)d_ws);
        mdn_fused<true><<<grid, 128, 0, stream>>>(
            (const float*)d_in[0],
            (const float*)d_in[1], (const float*)d_in[2],
            (const float*)d_in[3], (const float*)d_in[4],
            (const float*)d_in[5], (const float*)d_in[6],
            (const float*)d_in[7], (const float*)d_in[8],
            (const float*)d_in[9], (const float*)d_in[10],
            (const float*)d_in[11], (const float*)d_in[12],
            (float*)d_out, (const double*)d_ws);
    } else {
        mdn_fused<false><<<grid, 128, 0, stream>>>(
            (const float*)d_in[0],
            (const float*)d_in[1], (const float*)d_in[2],
            (const float*)d_in[3], (const float*)d_in[4],
            (const float*)d_in[5], (const float*)d_in[6],
            (const float*)d_in[7], (const float*)d_in[8],
            (const float*)d_in[9], (const float*)d_in[10],
            (const float*)d_in[11], (const float*)d_in[12],
            (float*)d_out, nullptr);
    }
}

// Round 11
// 155.047 us; speedup vs baseline: 3.1809x; 3.1809x over previous
//
#include <hip/hip_runtime.h>
#include <cmath>

// Problem constants: B=32768, N=17, D=2, K=3, H=64
#define NBATCH 32768
#define NJOINT 17
#define OUT0_ELEMS (NBATCH * NJOINT * 15)          // out[B,N,3,5]
#define KJS_OFF    OUT0_ELEMS                      // k_js[B,N]
#define MASK_OFF   (KJS_OFF + NBATCH * NJOINT)     // mask[B,N,3]

#define WN_STRIDE 774
#define WS_DOUBLES (NJOINT * WN_STRIDE)

// Intermediate between kernel A and kernel B: per point {p0,p1,p2, pack}.
// pack = kj | i0<<2 | i1<<4 | i2<<6. Layout [n][b] -> coalesced in both
// kernels. Static device buffer: no hipMalloc, graph-capture safe.
__device__ __align__(16) float4 g_inter[NBATCH * NJOINT];   // 8.9 MB

__device__ __forceinline__ float sel3f(int i, float a, float b, float c) {
    return (i == 0) ? a : ((i == 1) ? b : c);
}

// --------------------------------------------------------------------------
// Prelude: fp64 copies of k/w weights (escape path only).
// --------------------------------------------------------------------------
__global__ void cvt_weights_f64(
    const float* __restrict__ kW1, const float* __restrict__ kb1,
    const float* __restrict__ kW2, const float* __restrict__ kb2,
    const float* __restrict__ wW1, const float* __restrict__ wb1,
    const float* __restrict__ wW2, const float* __restrict__ wb2,
    double* __restrict__ dws)
{
    const int n = blockIdx.x;
    double* o = dws + (size_t)n * WN_STRIDE;
    for (int i = threadIdx.x; i < WN_STRIDE; i += blockDim.x) {
        int j = i;
        const float* W1 = kW1; const float* b1 = kb1;
        const float* W2 = kW2; const float* b2 = kb2;
        if (j >= 387) { j -= 387; W1 = wW1; b1 = wb1; W2 = wW2; b2 = wb2; }
        float v;
        if (j < 128)      v = W1[n * 128 + j];
        else if (j < 192) v = b1[n * 64 + (j - 128)];
        else if (j < 384) v = W2[n * 192 + (j - 192)];
        else              v = b2[n * 3 + (j - 384)];
        o[i] = (double)v;
    }
}

// --------------------------------------------------------------------------
// fp32 MLP (2 -> 64 -> 3) for TWO points, one s_load weight stream.
// --------------------------------------------------------------------------
__device__ __forceinline__ void mlp32_2(
    const float* __restrict__ W1, const float* __restrict__ b1f,
    const float* __restrict__ W2f, const float* __restrict__ b2f, int n,
    float xA0, float xA1, float xB0, float xB1,
    float& lA0, float& lA1, float& lA2,
    float& lB0, float& lB1, float& lB2)
{
    const float* W1a = W1 + n * 128;
    const float* W1b = W1a + 64;
    const float* b1  = b1f + n * 64;
    const float* W2  = W2f + n * 192;
    lA0 = b2f[n * 3 + 0]; lB0 = lA0;
    lA1 = b2f[n * 3 + 1]; lB1 = lA1;
    lA2 = b2f[n * 3 + 2]; lB2 = lA2;
    #pragma unroll 4
    for (int h = 0; h < 64; ++h) {
        const float wa = W1a[h], wb = W1b[h], bb = b1[h];
        const float w0 = W2[h * 3 + 0], w1 = W2[h * 3 + 1], w2 = W2[h * 3 + 2];
        float hvA = fmaxf(fmaf(xA1, wb, fmaf(xA0, wa, bb)), 0.0f);
        float hvB = fmaxf(fmaf(xB1, wb, fmaf(xB0, wa, bb)), 0.0f);
        lA0 = fmaf(hvA, w0, lA0); lB0 = fmaf(hvB, w0, lB0);
        lA1 = fmaf(hvA, w1, lA1); lB1 = fmaf(hvB, w1, lB1);
        lA2 = fmaf(hvA, w2, lA2); lB2 = fmaf(hvB, w2, lB2);
    }
}

// --------------------------------------------------------------------------
// fp64 escape: EXACT sequence of the proven passing kernels.
// --------------------------------------------------------------------------
__device__ __forceinline__ void mlp64_ws_1(
    const double* __restrict__ gws, double x0, double x1,
    double& l0, double& l1, double& l2)
{
    const double* W1a = gws;
    const double* W1b = gws + 64;
    const double* b1  = gws + 128;
    const double* W2  = gws + 192;
    l0 = gws[384]; l1 = gws[385]; l2 = gws[386];
    #pragma unroll 4
    for (int h = 0; h < 64; ++h) {
        double hv = fmax(fma(x1, W1b[h], fma(x0, W1a[h], b1[h])), 0.0);
        l0 = fma(hv, W2[h * 3 + 0], l0);
        l1 = fma(hv, W2[h * 3 + 1], l1);
        l2 = fma(hv, W2[h * 3 + 2], l2);
    }
}

__device__ __forceinline__ void mlp64_cvt_1(
    const float* __restrict__ W1, const float* __restrict__ b1f,
    const float* __restrict__ W2f, const float* __restrict__ b2f, int n,
    double x0, double x1, double& l0, double& l1, double& l2)
{
    const float* W1a = W1 + n * 128;
    const float* W1b = W1a + 64;
    const float* b1  = b1f + n * 64;
    const float* W2  = W2f + n * 192;
    l0 = (double)b2f[n * 3 + 0];
    l1 = (double)b2f[n * 3 + 1];
    l2 = (double)b2f[n * 3 + 2];
    #pragma unroll 4
    for (int h = 0; h < 64; ++h) {
        double hv = fma(x1, (double)W1b[h], fma(x0, (double)W1a[h], (double)b1[h]));
        hv = fmax(hv, 0.0);
        l0 = fma(hv, (double)W2[h * 3 + 0], l0);
        l1 = fma(hv, (double)W2[h * 3 + 1], l1);
        l2 = fma(hv, (double)W2[h * 3 + 2], l2);
    }
}

// margin check (r9-proven): ~3% wave escape rate.
__device__ __forceinline__ bool tight3(float a, float b, float c) {
    const float m01 = fabsf(a - b), m02 = fabsf(a - c), m12 = fabsf(b - c);
    const float mn = fminf(m01, fminf(m02, m12));
    const float tau = 2e-5f * (1.0f + 0.05f * (fabsf(a) + fabsf(b) + fabsf(c)));
    return mn < tau;
}

// decisions + softmax from (double) logits — identical to passing kernels.
__device__ __forceinline__ void decide(
    double kl0, double kl1, double kl2,
    double wl0, double wl1, double wl2,
    int& kj, int& i0, int& i1, int& i2,
    float& p0, float& p1, float& p2)
{
    kj = 0;
    {
        double m = kl0;
        if (kl1 > m) { m = kl1; kj = 1; }
        if (kl2 > m) { kj = 2; }
    }
    i0 = 0;
    {
        double m = wl0;
        if (wl1 > m) { m = wl1; i0 = 1; }
        if (wl2 > m) { i0 = 2; }
    }
    const int ia = (i0 == 0) ? 1 : 0;
    const int ib = (i0 == 2) ? 1 : 2;
    const double wa = ia ? wl1 : wl0;
    const double wb = (ib == 1) ? wl1 : wl2;
    i1 = (wb > wa) ? ib : ia;
    i2 = (wb > wa) ? ia : ib;

    const double mw = fmax(fmax(wl0, wl1), wl2);
    const float e0 = __expf((float)(wl0 - mw));
    const float e1 = __expf((float)(wl1 - mw));
    const float e2 = __expf((float)(wl2 - mw));
    const float inv = 1.0f / (e0 + e1 + e2);
    p0 = e0 * inv; p1 = e1 * inv; p2 = e2 * inv;
}

__device__ __forceinline__ void epilogue(
    const float acc[12], int i0, int i1, int i2,
    float p0, float p1, float p2, float r[15])
{
    r[0]  = p0; r[5] = p1; r[10] = p2;
    r[1]  = sel3f(i0, acc[0], acc[4], acc[8]);
    r[2]  = sel3f(i0, acc[1], acc[5], acc[9]);
    r[3]  = __expf(sel3f(i0, acc[2], acc[6], acc[10]));
    r[4]  = __expf(sel3f(i0, acc[3], acc[7], acc[11]));
    r[6]  = sel3f(i1, acc[0], acc[4], acc[8]);
    r[7]  = sel3f(i1, acc[1], acc[5], acc[9]);
    r[8]  = __expf(sel3f(i1, acc[2], acc[6], acc[10]));
    r[9]  = __expf(sel3f(i1, acc[3], acc[7], acc[11]));
    r[11] = sel3f(i2, acc[0], acc[4], acc[8]);
    r[12] = sel3f(i2, acc[1], acc[5], acc[9]);
    r[13] = __expf(sel3f(i2, acc[2], acc[6], acc[10]));
    r[14] = __expf(sel3f(i2, acc[3], acc[7], acc[11]));
}

// ==========================================================================
// KERNEL A: k/w MLPs + decide. Scalar working set = 2 n x 3.1 KB = 6.2 KB
// (fits the 16 KB K$). Writes 16 B/point intermediates, [n][b] coalesced.
// No LDS, no barriers.
// ==========================================================================
template<bool USE_WS>
__global__ __launch_bounds__(128, 4) void mdn_kw(
    const float* __restrict__ pred_pts,
    const float* __restrict__ kW1, const float* __restrict__ kb1,
    const float* __restrict__ kW2, const float* __restrict__ kb2,
    const float* __restrict__ wW1, const float* __restrict__ wb1,
    const float* __restrict__ wW2, const float* __restrict__ wb2,
    const double* __restrict__ dws)
{
    const int l    = threadIdx.x;
    const int w    = l >> 6;
    const int lane = l & 63;
    const int bx   = blockIdx.x;       // 0..255
    const int by   = blockIdx.y;       // 0..8
    const int n0   = by * 2;

    if (by == 8 && w == 1) return;     // no barriers anywhere in this kernel
    int n = n0 + w;
    n = __builtin_amdgcn_readfirstlane(n);

    const int bA = bx * 128 + lane;
    const int bB = bA + 64;
    const int pA = bA * NJOINT + n;
    const int pB = bB * NJOINT + n;

    const float2 xA = *reinterpret_cast<const float2*>(pred_pts + 2 * pA);
    const float2 xB = *reinterpret_cast<const float2*>(pred_pts + 2 * pB);

    float kA0, kA1, kA2, kB0, kB1, kB2;
    float wA0, wA1, wA2, wB0, wB1, wB2;
    mlp32_2(kW1, kb1, kW2, kb2, n, xA.x, xA.y, xB.x, xB.y,
            kA0, kA1, kA2, kB0, kB1, kB2);
    mlp32_2(wW1, wb1, wW2, wb2, n, xA.x, xA.y, xB.x, xB.y,
            wA0, wA1, wA2, wB0, wB1, wB2);

    const bool fA = tight3(kA0, kA1, kA2) || tight3(wA0, wA1, wA2);
    const bool fB = tight3(kB0, kB1, kB2) || tight3(wB0, wB1, wB2);

    double klA0 = kA0, klA1 = kA1, klA2 = kA2;
    double klB0 = kB0, klB1 = kB1, klB2 = kB2;
    double wlA0 = wA0, wlA1 = wA1, wlA2 = wA2;
    double wlB0 = wB0, wlB1 = wB1, wlB2 = wB2;

    if (__any(fA || fB)) {             // ~3% of waves
        if constexpr (USE_WS) {
            const double* Wn = dws + (size_t)n * WN_STRIDE;
            if (fA) {
                mlp64_ws_1(Wn,       (double)xA.x, (double)xA.y, klA0, klA1, klA2);
                mlp64_ws_1(Wn + 387, (double)xA.x, (double)xA.y, wlA0, wlA1, wlA2);
            }
            if (fB) {
                mlp64_ws_1(Wn,       (double)xB.x, (double)xB.y, klB0, klB1, klB2);
                mlp64_ws_1(Wn + 387, (double)xB.x, (double)xB.y, wlB0, wlB1, wlB2);
            }
        } else {
            if (fA) {
                mlp64_cvt_1(kW1, kb1, kW2, kb2, n, (double)xA.x, (double)xA.y, klA0, klA1, klA2);
                mlp64_cvt_1(wW1, wb1, wW2, wb2, n, (double)xA.x, (double)xA.y, wlA0, wlA1, wlA2);
            }
            if (fB) {
                mlp64_cvt_1(kW1, kb1, kW2, kb2, n, (double)xB.x, (double)xB.y, klB0, klB1, klB2);
                mlp64_cvt_1(wW1, wb1, wW2, wb2, n, (double)xB.x, (double)xB.y, wlB0, wlB1, wlB2);
            }
        }
    }

    int kjA, i0A, i1A, i2A, kjB, i0B, i1B, i2B;
    float p0A, p1A, p2A, p0B, p1B, p2B;
    decide(klA0, klA1, klA2, wlA0, wlA1, wlA2, kjA, i0A, i1A, i2A, p0A, p1A, p2A);
    decide(klB0, klB1, klB2, wlB0, wlB1, wlB2, kjB, i0B, i1B, i2B, p0B, p1B, p2B);

    const int packA = kjA | (i0A << 2) | (i1A << 4) | (i2A << 6);
    const int packB = kjB | (i0B << 2) | (i1B << 4) | (i2B << 6);
    g_inter[n * NBATCH + bA] = make_float4(p0A, p1A, p2A, __int_as_float(packA));
    g_inter[n * NBATCH + bB] = make_float4(p0B, p1B, p2B, __int_as_float(packB));
}

// ==========================================================================
// KERNEL B: bMLP + epilogue + staged coalesced stores (r9 structure).
// Scalar working set = 2 n x 7.7 KB = 15.4 KB (fits K$).
// ==========================================================================
__global__ __launch_bounds__(128, 4) void mdn_b(
    const float* __restrict__ pred_pts,
    const float* __restrict__ bW1, const float* __restrict__ bb1,
    const float* __restrict__ bW2, const float* __restrict__ bb2,
    float* __restrict__ out)
{
    const int l    = threadIdx.x;
    const int w    = l >> 6;
    const int lane = l & 63;
    const int bx   = blockIdx.x;       // 0..255
    const int by   = blockIdx.y;       // 0..8
    const int n0   = by * 2;

    if (by == 8 && w == 1) return;     // before any barrier
    int n = n0 + w;
    n = __builtin_amdgcn_readfirstlane(n);

    const int bA = bx * 128 + lane;
    const int bB = bA + 64;
    const int pA = bA * NJOINT + n;
    const int pB = bB * NJOINT + n;

    const float2 xA = *reinterpret_cast<const float2*>(pred_pts + 2 * pA);
    const float2 xB = *reinterpret_cast<const float2*>(pred_pts + 2 * pB);

    const float4 qA = g_inter[n * NBATCH + bA];
    const float4 qB = g_inter[n * NBATCH + bB];
    const int packA = __float_as_int(qA.w);
    const int packB = __float_as_int(qB.w);
    const int kjA = packA & 3, i0A = (packA >> 2) & 3, i1A = (packA >> 4) & 3, i2A = (packA >> 6) & 3;
    const int kjB = packB & 3, i0B = (packB >> 2) & 3, i1B = (packB >> 4) & 3, i2B = (packB >> 6) & 3;

    // ---- bMLP (fp32): 2 -> 128 -> 12, shared s_load stream (r9-proven) ----
    float accA[12], accB[12];
    {
        const float* W1a = bW1 + n * 256;
        const float* W1b = W1a + 128;
        const float* b1  = bb1 + n * 128;
        const float* W2  = bW2 + n * 1536;
        const float* b2  = bb2 + n * 12;
        #pragma unroll
        for (int j = 0; j < 12; ++j) { accA[j] = b2[j]; accB[j] = b2[j]; }
        #pragma unroll 4
        for (int h = 0; h < 128; ++h) {
            const float wa = W1a[h], wb = W1b[h], bb = b1[h];
            float hvA = fmaxf(fmaf(xA.y, wb, fmaf(xA.x, wa, bb)), 0.0f);
            float hvB = fmaxf(fmaf(xB.y, wb, fmaf(xB.x, wa, bb)), 0.0f);
            #pragma unroll
            for (int j = 0; j < 12; ++j) {
                const float wv = W2[h * 12 + j];
                accA[j] = fmaf(hvA, wv, accA[j]);
                accB[j] = fmaf(hvB, wv, accB[j]);
            }
        }
    }

    float rA[15], rB[15];
    epilogue(accA, i0A, i1A, i2A, qA.x, qA.y, qA.z, rA);
    epilogue(accB, i0B, i1B, i2B, qB.x, qB.y, qB.z, rB);

    if (by == 8) {
        // n==16 remainder: direct stores, no barriers.
        float* oA = out + (size_t)pA * 15;
        float* oB = out + (size_t)pB * 15;
        #pragma unroll
        for (int i = 0; i < 15; ++i) { oA[i] = rA[i]; oB[i] = rB[i]; }
        out[KJS_OFF + pA] = (float)(kjA + 1);
        out[KJS_OFF + pB] = (float)(kjB + 1);
        float* mkA = out + MASK_OFF + (size_t)pA * 3;
        mkA[0] = 1.0f; mkA[1] = (kjA >= 1) ? 1.0f : 0.0f; mkA[2] = (kjA >= 2) ? 1.0f : 0.0f;
        float* mkB = out + MASK_OFF + (size_t)pB * 3;
        mkB[0] = 1.0f; mkB[1] = (kjB >= 1) ? 1.0f : 0.0f; mkB[2] = (kjB >= 2) ? 1.0f : 0.0f;
        return;
    }

    // ---- stage tile in LDS: slot = w*128 + local_b, stride 17 dwords ----
    __shared__ float s_out[256 * 17];  // 17408 B
    {
        float* soA = s_out + (w * 128 + lane) * 17;
        float* soB = soA + 64 * 17;
        #pragma unroll
        for (int j = 0; j < 15; ++j) { soA[j] = rA[j]; soB[j] = rB[j]; }
        soA[15] = (float)(kjA + 1);
        soB[15] = (float)(kjB + 1);
    }
    __syncthreads();

    // ---- coalesced write-back: 32 rounds, lanes 0..119 ----
    if (l < 120) {
        const int c_off = l / 30;
        const int jj    = l - c_off * 30;
        const int nl    = jj / 15;
        const int j     = jj - nl * 15;
        const int lbase = (nl * 128 + c_off) * 17 + j;
        size_t g = (size_t)((bx * 128 + c_off) * NJOINT + n0) * 15 + jj;
        #pragma unroll
        for (int rr = 0; rr < 32; ++rr) {
            out[g] = s_out[lbase + 68 * rr];
            g += 1020;
        }
    }

    // ---- k_js + mask from staged kj, per-b contiguous pairs ----
    #pragma unroll
    for (int it = 0; it < 2; ++it) {
        const int q   = it * 128 + l;
        const int bl  = q >> 1;
        const int nlr = q & 1;
        const float kjf = s_out[(nlr * 128 + bl) * 17 + 15];
        const int pg = (bx * 128 + bl) * NJOINT + n0 + nlr;
        out[KJS_OFF + pg] = kjf;
        float* mk = out + MASK_OFF + (size_t)pg * 3;
        mk[0] = 1.0f;
        mk[1] = (kjf >= 1.5f) ? 1.0f : 0.0f;
        mk[2] = (kjf >= 2.5f) ? 1.0f : 0.0f;
    }
}

extern "C" void kernel_launch(void* const* d_in, const int* in_sizes, int n_in,
                              void* d_out, int out_size, void* d_ws, size_t ws_size,
                              hipStream_t stream) {
    (void)in_sizes; (void)n_in; (void)out_size;
    const bool use_ws = (d_ws != nullptr) && (ws_size >= (size_t)WS_DOUBLES * sizeof(double));
    dim3 grid(NBATCH / 128, 9);

    if (use_ws) {
        cvt_weights_f64<<<NJOINT, 256, 0, stream>>>(
            (const float*)d_in[1], (const float*)d_in[2],
            (const float*)d_in[3], (const float*)d_in[4],
            (const float*)d_in[5], (const float*)d_in[6],
            (const float*)d_in[7], (const float*)d_in[8],
            (double*)d_ws);
        mdn_kw<true><<<grid, 128, 0, stream>>>(
            (const float*)d_in[0],
            (const float*)d_in[1], (const float*)d_in[2],
            (const float*)d_in[3], (const float*)d_in[4],
            (const float*)d_in[5], (const float*)d_in[6],
            (const float*)d_in[7], (const float*)d_in[8],
            (const double*)d_ws);
    } else {
        mdn_kw<false><<<grid, 128, 0, stream>>>(
            (const float*)d_in[0],
            (const float*)d_in[1], (const float*)d_in[2],
            (const float*)d_in[3], (const float*)d_in[4],
            (const float*)d_in[5], (const float*)d_in[6],
            (const float*)d_in[7], (const float*)d_in[8],
            nullptr);
    }

    mdn_b<<<grid, 128, 0, stream>>>(
        (const float*)d_in[0],
        (const float*)d_in[9], (const float*)d_in[10],
        (const float*)d_in[11], (const float*)d_in[12],
        (float*)d_out);
}